// Round 5
// baseline (116.739 us; speedup 1.0000x reference)
//
#include <hip/hip_runtime.h>

// KroneSoftmax: x[2, 2048, 256] fp32.
// out[b, a*256+k] = softmax_row( x[0][b,a] * x[1][b,k] )
// Round 4: two-kernel split. K1 computes per-row fused softmax constant
// C[row] = -M*log2e - log2(sum) into d_ws (tiny, ~5us). K2 is a pure
// streaming-store kernel with no barriers: out = exp2(a*(b*log2e) + C).
// Rationale: fused kernel exposed ~20us of GPU-wide reduction prologue
// (trans-unit bound) before any HBM writes started.

constexpr int FA   = 256;
constexpr int FB   = 256;
constexpr int ROWS = 2048;
constexpr float LOG2E = 1.4426950408889634f;

typedef float f32x4 __attribute__((ext_vector_type(4)));

// ---------------- K1: per-row reduction -> C[row] ----------------
__global__ __launch_bounds__(256) void krone_reduce_kernel(
    const float* __restrict__ x, float* __restrict__ Cbuf) {
  const int row = blockIdx.x;
  const int tid = threadIdx.x;

  const float* __restrict__ xa = x + (size_t)row * FA;
  const float* __restrict__ xb = x + (size_t)ROWS * FA + (size_t)row * FB;

  __shared__ float sa[FA];
  __shared__ float wred[4][4];
  __shared__ float wsum[4];

  const float a = xa[tid];
  const float b = xb[tid];
  sa[tid] = a;

  // max/min of each vector via butterfly; bilinear max from extremes (exact)
  float maxa = a, mina = a, maxb = b, minb = b;
#pragma unroll
  for (int off = 32; off > 0; off >>= 1) {
    maxa = fmaxf(maxa, __shfl_xor(maxa, off));
    mina = fminf(mina, __shfl_xor(mina, off));
    maxb = fmaxf(maxb, __shfl_xor(maxb, off));
    minb = fminf(minb, __shfl_xor(minb, off));
  }
  const int wid = tid >> 6;
  if ((tid & 63) == 0) {
    wred[wid][0] = maxa; wred[wid][1] = mina;
    wred[wid][2] = maxb; wred[wid][3] = minb;
  }
  __syncthreads();
  const float MA = fmaxf(fmaxf(wred[0][0], wred[1][0]), fmaxf(wred[2][0], wred[3][0]));
  const float mA = fminf(fminf(wred[0][1], wred[1][1]), fminf(wred[2][1], wred[3][1]));
  const float MB = fmaxf(fmaxf(wred[0][2], wred[1][2]), fmaxf(wred[2][2], wred[3][2]));
  const float mB = fminf(fminf(wred[0][3], wred[1][3]), fminf(wred[2][3], wred[3][3]));
  const float M = fmaxf(fmaxf(MA * MB, MA * mB), fmaxf(mA * MB, mA * mB));
  const float mM2 = -M * LOG2E;

  // denominator: thread owns column tid, loops a-rows (LDS broadcast)
  const float bs = b * LOG2E;
  float s0 = 0.f, s1 = 0.f, s2 = 0.f, s3 = 0.f;
#pragma unroll 4
  for (int i = 0; i < FA; i += 4) {
    s0 += __builtin_amdgcn_exp2f(fmaf(sa[i + 0], bs, mM2));
    s1 += __builtin_amdgcn_exp2f(fmaf(sa[i + 1], bs, mM2));
    s2 += __builtin_amdgcn_exp2f(fmaf(sa[i + 2], bs, mM2));
    s3 += __builtin_amdgcn_exp2f(fmaf(sa[i + 3], bs, mM2));
  }
  float s = (s0 + s1) + (s2 + s3);
#pragma unroll
  for (int off = 32; off > 0; off >>= 1) s += __shfl_xor(s, off);
  if ((tid & 63) == 0) wsum[wid] = s;
  __syncthreads();
  if (tid == 0) {
    const float sum = (wsum[0] + wsum[1]) + (wsum[2] + wsum[3]);
    Cbuf[row] = mM2 - __builtin_amdgcn_logf(sum);
  }
}

// ---------------- K2: pure streaming stores, no barriers ----------------
__global__ __launch_bounds__(256) void krone_store_kernel(
    const float* __restrict__ x, const float* __restrict__ Cbuf,
    float* __restrict__ out) {
  const int row = blockIdx.x;
  const int tid = threadIdx.x;
  const int wid = tid >> 6;
  const int lane = tid & 63;

  const float* __restrict__ xa = x + (size_t)row * FA;
  const float* __restrict__ xb = x + (size_t)ROWS * FA + (size_t)row * FB;

  // per-lane register copy of this wave's 64 a-values (coalesced 256B load)
  const float aval = xa[wid * 64 + lane];
  // b-fragment: direct global vector load (L2/L1-hot, 16B aligned)
  const int j = lane * 4;
  f32x4 b4 = *reinterpret_cast<const f32x4*>(&xb[j]);
  b4 *= LOG2E;
  const float C = Cbuf[row];  // wave-uniform broadcast load

  float* __restrict__ oseg = out + (size_t)row * (FA * FB) + wid * (64 * FB);
#pragma unroll 8
  for (int it = 0; it < 64; ++it) {
    const float av = __shfl(aval, it);  // broadcast a[w*64+it] from lane it
    f32x4 v;
    v.x = __builtin_amdgcn_exp2f(fmaf(av, b4.x, C));
    v.y = __builtin_amdgcn_exp2f(fmaf(av, b4.y, C));
    v.z = __builtin_amdgcn_exp2f(fmaf(av, b4.z, C));
    v.w = __builtin_amdgcn_exp2f(fmaf(av, b4.w, C));
    __builtin_nontemporal_store(v, reinterpret_cast<f32x4*>(&oseg[it * FB + j]));
  }
}

// ---------------- fallback: fused single kernel (ws too small) ----------------
__global__ __launch_bounds__(256) void krone_fused_kernel(
    const float* __restrict__ x, float* __restrict__ out) {
  const int row = blockIdx.x;
  const int tid = threadIdx.x;
  const float* __restrict__ xa = x + (size_t)row * FA;
  const float* __restrict__ xb = x + (size_t)ROWS * FA + (size_t)row * FB;
  __shared__ float sa[FA];
  __shared__ float sb[FB];
  __shared__ float wred[4][4];
  __shared__ float wsum[4];
  const float a = xa[tid];
  const float b = xb[tid];
  sa[tid] = a; sb[tid] = b;
  float maxa = a, mina = a, maxb = b, minb = b;
#pragma unroll
  for (int off = 32; off > 0; off >>= 1) {
    maxa = fmaxf(maxa, __shfl_xor(maxa, off));
    mina = fminf(mina, __shfl_xor(mina, off));
    maxb = fmaxf(maxb, __shfl_xor(maxb, off));
    minb = fminf(minb, __shfl_xor(minb, off));
  }
  const int wid = tid >> 6;
  if ((tid & 63) == 0) {
    wred[wid][0] = maxa; wred[wid][1] = mina;
    wred[wid][2] = maxb; wred[wid][3] = minb;
  }
  __syncthreads();
  const float MA = fmaxf(fmaxf(wred[0][0], wred[1][0]), fmaxf(wred[2][0], wred[3][0]));
  const float mA = fminf(fminf(wred[0][1], wred[1][1]), fminf(wred[2][1], wred[3][1]));
  const float MB = fmaxf(fmaxf(wred[0][2], wred[1][2]), fmaxf(wred[2][2], wred[3][2]));
  const float mB = fminf(fminf(wred[0][3], wred[1][3]), fminf(wred[2][3], wred[3][3]));
  const float M = fmaxf(fmaxf(MA * MB, MA * mB), fmaxf(mA * MB, mA * mB));
  const float mM2 = -M * LOG2E;
  const float bs = b * LOG2E;
  float s0 = 0.f, s1 = 0.f, s2 = 0.f, s3 = 0.f;
#pragma unroll 4
  for (int i = 0; i < FA; i += 4) {
    s0 += __builtin_amdgcn_exp2f(fmaf(sa[i + 0], bs, mM2));
    s1 += __builtin_amdgcn_exp2f(fmaf(sa[i + 1], bs, mM2));
    s2 += __builtin_amdgcn_exp2f(fmaf(sa[i + 2], bs, mM2));
    s3 += __builtin_amdgcn_exp2f(fmaf(sa[i + 3], bs, mM2));
  }
  float s = (s0 + s1) + (s2 + s3);
#pragma unroll
  for (int off = 32; off > 0; off >>= 1) s += __shfl_xor(s, off);
  if ((tid & 63) == 0) wsum[wid] = s;
  __syncthreads();
  const float sum = (wsum[0] + wsum[1]) + (wsum[2] + wsum[3]);
  const float C = mM2 - __builtin_amdgcn_logf(sum);
  float* __restrict__ orow = out + (size_t)row * (FA * FB);
  const int lane = tid & 63;
  const int j = lane * 4;
  f32x4 b4 = *reinterpret_cast<const f32x4*>(&sb[j]);
  b4 *= LOG2E;
  float* __restrict__ oseg = orow + wid * (64 * FB);
#pragma unroll 8
  for (int it = 0; it < 64; ++it) {
    const float av = sa[wid * 64 + it];
    f32x4 v;
    v.x = __builtin_amdgcn_exp2f(fmaf(av, b4.x, C));
    v.y = __builtin_amdgcn_exp2f(fmaf(av, b4.y, C));
    v.z = __builtin_amdgcn_exp2f(fmaf(av, b4.z, C));
    v.w = __builtin_amdgcn_exp2f(fmaf(av, b4.w, C));
    __builtin_nontemporal_store(v, reinterpret_cast<f32x4*>(&oseg[it * FB + j]));
  }
}

extern "C" void kernel_launch(void* const* d_in, const int* in_sizes, int n_in,
                              void* d_out, int out_size, void* d_ws, size_t ws_size,
                              hipStream_t stream) {
  const float* x = (const float*)d_in[0];
  float* out = (float*)d_out;
  if (ws_size >= ROWS * sizeof(float)) {
    float* Cbuf = (float*)d_ws;
    krone_reduce_kernel<<<ROWS, 256, 0, stream>>>(x, Cbuf);
    krone_store_kernel<<<ROWS, 256, 0, stream>>>(x, Cbuf, out);
  } else {
    krone_fused_kernel<<<ROWS, 256, 0, stream>>>(x, out);
  }
}

// Round 6
// 109.374 us; speedup vs baseline: 1.0673x; 1.0673x over previous
//
#include <hip/hip_runtime.h>

// KroneSoftmax: x[2, 2048, 256] fp32.
// out[b, a*256+k] = softmax_row( x[0][b,a] * x[1][b,k] )
// Round 5: LOW-CONCURRENCY fused kernel. 512 blocks (2/CU), each handles 4
// contiguous rows serially -> ~2048 write streams instead of 8192. Mimics the
// fill kernel's shape (6.7 TB/s at 10% occupancy): few, long, sequential
// per-wave streams so memory-controller reorder windows can merge them.
// Inner code identical to round 3 (which passed).

constexpr int FA   = 256;
constexpr int FB   = 256;
constexpr int ROWS = 2048;
constexpr int RPB  = 4;            // rows per block
constexpr float LOG2E = 1.4426950408889634f;

typedef float f32x4 __attribute__((ext_vector_type(4)));

__global__ __launch_bounds__(256) void krone_softmax_kernel(
    const float* __restrict__ x, float* __restrict__ out) {
  const int tid  = threadIdx.x;
  const int wid  = tid >> 6;
  const int lane = tid & 63;
  const int j    = lane * 4;
  const int row0 = blockIdx.x * RPB;

  __shared__ float sa[FA];
  __shared__ float wred[4][4];
  __shared__ float wsum[4];

  for (int r = 0; r < RPB; ++r) {
    const int row = row0 + r;
    const float* __restrict__ xa = x + (size_t)row * FA;
    const float* __restrict__ xb = x + (size_t)ROWS * FA + (size_t)row * FB;

    const float a = xa[tid];
    const float b = xb[tid];
    f32x4 b4 = *reinterpret_cast<const f32x4*>(&xb[j]);   // L1-hot after warm
    __syncthreads();                 // protect sa from previous row's readers
    sa[tid] = a;

    // ---- row max of bilinear form via vector extremes (exact) ----
    float maxa = a, mina = a, maxb = b, minb = b;
#pragma unroll
    for (int off = 32; off > 0; off >>= 1) {
      maxa = fmaxf(maxa, __shfl_xor(maxa, off));
      mina = fminf(mina, __shfl_xor(mina, off));
      maxb = fmaxf(maxb, __shfl_xor(maxb, off));
      minb = fminf(minb, __shfl_xor(minb, off));
    }
    if (lane == 0) {
      wred[wid][0] = maxa; wred[wid][1] = mina;
      wred[wid][2] = maxb; wred[wid][3] = minb;
    }
    __syncthreads();
    const float MA = fmaxf(fmaxf(wred[0][0], wred[1][0]), fmaxf(wred[2][0], wred[3][0]));
    const float mA = fminf(fminf(wred[0][1], wred[1][1]), fminf(wred[2][1], wred[3][1]));
    const float MB = fmaxf(fmaxf(wred[0][2], wred[1][2]), fmaxf(wred[2][2], wred[3][2]));
    const float mB = fminf(fminf(wred[0][3], wred[1][3]), fminf(wred[2][3], wred[3][3]));
    const float M = fmaxf(fmaxf(MA * MB, MA * mB), fmaxf(mA * MB, mA * mB));
    const float mM2 = -M * LOG2E;

    // ---- denominator: thread owns column tid, loop over a rows ----
    const float bs = b * LOG2E;
    float s0 = 0.f, s1 = 0.f, s2 = 0.f, s3 = 0.f;
#pragma unroll 4
    for (int i = 0; i < FA; i += 4) {
      s0 += __builtin_amdgcn_exp2f(fmaf(sa[i + 0], bs, mM2));
      s1 += __builtin_amdgcn_exp2f(fmaf(sa[i + 1], bs, mM2));
      s2 += __builtin_amdgcn_exp2f(fmaf(sa[i + 2], bs, mM2));
      s3 += __builtin_amdgcn_exp2f(fmaf(sa[i + 3], bs, mM2));
    }
    float s = (s0 + s1) + (s2 + s3);
#pragma unroll
    for (int off = 32; off > 0; off >>= 1) s += __shfl_xor(s, off);
    if (lane == 0) wsum[wid] = s;
    __syncthreads();
    const float sum = (wsum[0] + wsum[1]) + (wsum[2] + wsum[3]);

    // out = exp2( a*(b*log2e) + C ),  C = -M*log2e - log2(sum)
    const float C = mM2 - __builtin_amdgcn_logf(sum);

    // ---- store: wave w owns a-rows [w*64, w*64+64) => contiguous 64 KB ----
    f32x4 b4s = b4 * LOG2E;
    float* __restrict__ oseg =
        out + (size_t)row * (FA * FB) + wid * (64 * FB);
#pragma unroll 8
    for (int it = 0; it < 64; ++it) {
      const float av = sa[wid * 64 + it];  // wave-uniform broadcast
      f32x4 v;
      v.x = __builtin_amdgcn_exp2f(fmaf(av, b4s.x, C));
      v.y = __builtin_amdgcn_exp2f(fmaf(av, b4s.y, C));
      v.z = __builtin_amdgcn_exp2f(fmaf(av, b4s.z, C));
      v.w = __builtin_amdgcn_exp2f(fmaf(av, b4s.w, C));
      __builtin_nontemporal_store(v, reinterpret_cast<f32x4*>(&oseg[it * FB + j]));
    }
  }
}

extern "C" void kernel_launch(void* const* d_in, const int* in_sizes, int n_in,
                              void* d_out, int out_size, void* d_ws, size_t ws_size,
                              hipStream_t stream) {
  const float* x = (const float*)d_in[0];
  float* out = (float*)d_out;
  krone_softmax_kernel<<<ROWS / RPB, 256, 0, stream>>>(x, out);
}